// Round 2
// baseline (512.207 us; speedup 1.0000x reference)
//
#include <hip/hip_runtime.h>

// SE-block on MI355X.
// x: (32,512,56,56) f32, w1: (512,512,4,4), w2: (512,512,1,1), u1/u2: (512)
// Pipeline: pool+sigmoid -> spectral sigma1/sigma2 (scalars only) ->
//           h = relu(p.w1 / s1) -> s = sigmoid(h.w2 / s2) -> top-102 mask -> out = x*weight

#define KTOP 102

__device__ __forceinline__ float block_sum256(float v) {
  __shared__ float red[4];
  #pragma unroll
  for (int off = 32; off; off >>= 1) v += __shfl_down(v, off, 64);
  int lane = threadIdx.x & 63;
  int w = threadIdx.x >> 6;
  if (lane == 0) red[w] = v;
  __syncthreads();
  float r = 0.f;
  if (threadIdx.x == 0) r = red[0] + red[1] + red[2] + red[3];
  return r;  // valid on thread 0 only
}

// K1: adaptive avg-pool 4x4 (14x14 windows) + sigmoid. One block per (n,c) plane.
__global__ __launch_bounds__(256) void k_pool(const float* __restrict__ x, float* __restrict__ p) {
  __shared__ float sx[3136];
  int plane = blockIdx.x;
  const float* xp = x + (size_t)plane * 3136;
  for (int e = threadIdx.x; e < 3136; e += 256) sx[e] = xp[e];
  __syncthreads();
  int t = threadIdx.x;
  int w = t >> 4, lane = t & 15;
  int wr = w >> 2, wc = w & 3;
  float acc = 0.f;
  for (int e = lane; e < 196; e += 16) {
    int r = e / 14, cc = e - r * 14;
    acc += sx[(14 * wr + r) * 56 + 14 * wc + cc];
  }
  #pragma unroll
  for (int off = 8; off; off >>= 1) acc += __shfl_down(acc, off, 16);
  if (lane == 0) {
    float m = acc * (1.f / 196.f);
    p[(size_t)plane * 16 + w] = 1.f / (1.f + expf(-m));
  }
}

// K2: t1 = W^T u partials (column reduction, split over row-chunks of 64).
// blocks 0..255: w1 (32 j-blocks x 8 i-chunks). blocks 256..271: w2 (2 x 8).
__global__ __launch_bounds__(256) void k_sn1(const float* __restrict__ w1, const float* __restrict__ w2,
                                             const float* __restrict__ u1, const float* __restrict__ u2,
                                             float* __restrict__ part1, float* __restrict__ part1b) {
  __shared__ float su[64];
  int b = blockIdx.x, t = threadIdx.x;
  if (b < 256) {
    int jb = b & 31, ic = b >> 5;
    if (t < 64) su[t] = u1[ic * 64 + t];
    __syncthreads();
    int j = jb * 256 + t;
    const float* base = w1 + (size_t)(ic * 64) * 8192 + j;
    float acc = 0.f;
    #pragma unroll 4
    for (int i = 0; i < 64; ++i) acc += base[(size_t)i * 8192] * su[i];
    part1[ic * 8192 + j] = acc;
  } else {
    int bb = b - 256;
    int jb = bb & 1, ic = bb >> 1;
    if (t < 64) su[t] = u2[ic * 64 + t];
    __syncthreads();
    int j = jb * 256 + t;
    const float* base = w2 + (size_t)(ic * 64) * 512 + j;
    float acc = 0.f;
    #pragma unroll 4
    for (int i = 0; i < 64; ++i) acc += base[(size_t)i * 512] * su[i];
    part1b[ic * 512 + j] = acc;
  }
}

// K3: reduce partials -> t1 (unnormalized v), accumulate ||t1||^2 into scal[0]/scal[1].
__global__ __launch_bounds__(256) void k_sn1r(const float* __restrict__ part1, const float* __restrict__ part1b,
                                              float* __restrict__ t1, float* __restrict__ t1b,
                                              float* __restrict__ scal) {
  int b = blockIdx.x, t = threadIdx.x;
  float s = 0.f;
  if (b < 32) {
    int j = b * 256 + t;
    #pragma unroll
    for (int ic = 0; ic < 8; ++ic) s += part1[ic * 8192 + j];
    t1[j] = s;
    float tot = block_sum256(s * s);
    if (t == 0) atomicAdd(&scal[0], tot);
  } else {
    int j = (b - 32) * 256 + t;
    #pragma unroll
    for (int ic = 0; ic < 8; ++ic) s += part1b[ic * 512 + j];
    t1b[j] = s;
    float tot = block_sum256(s * s);
    if (t == 0) atomicAdd(&scal[1], tot);
  }
}

// K4: t2_i = (row_i . t1) / (||t1||+eps); accumulate ||t2||^2 -> scal[2]/scal[3].
// sigma = ||t2||^2 / (||t2|| + eps) computed by consumers.
__global__ __launch_bounds__(256) void k_sn2(const float* __restrict__ w1, const float* __restrict__ w2,
                                             const float* __restrict__ t1, const float* __restrict__ t1b,
                                             float* __restrict__ scal) {
  int b = blockIdx.x, t = threadIdx.x;
  if (b < 512) {
    float inv = 1.f / (sqrtf(scal[0]) + 1e-12f);
    const float4* row = (const float4*)(w1 + (size_t)b * 8192);
    const float4* tv = (const float4*)t1;
    float acc = 0.f;
    for (int q = t; q < 2048; q += 256) {
      float4 a = row[q], v = tv[q];
      acc += a.x * v.x + a.y * v.y + a.z * v.z + a.w * v.w;
    }
    float tot = block_sum256(acc);
    if (t == 0) { float r = tot * inv; atomicAdd(&scal[2], r * r); }
  } else {
    int i = b - 512;
    float inv = 1.f / (sqrtf(scal[1]) + 1e-12f);
    const float4* row = (const float4*)(w2 + (size_t)i * 512);
    const float4* tv = (const float4*)t1b;
    float acc = 0.f;
    if (t < 128) {
      float4 a = row[t], v = tv[t];
      acc = a.x * v.x + a.y * v.y + a.z * v.z + a.w * v.w;
    }
    float tot = block_sum256(acc);
    if (t == 0) { float r = tot * inv; atomicAdd(&scal[3], r * r); }
  }
}

// K5: h partials. grid (8 o-tiles x 64 k-splits). Each block: all 32 n, 64 o, 128 k.
// w1 is read exactly once from HBM across the whole grid.
__global__ __launch_bounds__(256) void k_gemm1(const float* __restrict__ p, const float* __restrict__ w1,
                                               float* __restrict__ part) {
  __shared__ float sp[32][132];
  __shared__ float sw[64][132];
  int t = threadIdx.x;
  int o0 = blockIdx.x * 64;
  int k0 = blockIdx.y * 128;
  for (int idx = t; idx < 32 * 128; idx += 256) {
    int r = idx >> 7, c = idx & 127;
    sp[r][c] = p[(size_t)r * 8192 + k0 + c];
  }
  for (int idx = t; idx < 64 * 128; idx += 256) {
    int r = idx >> 7, c = idx & 127;
    sw[r][c] = w1[(size_t)(o0 + r) * 8192 + k0 + c];
  }
  __syncthreads();
  int m = t & 31, g = t >> 5;
  int n0 = g * 4;
  float acc[4][2] = {{0.f, 0.f}, {0.f, 0.f}, {0.f, 0.f}, {0.f, 0.f}};
  for (int kk = 0; kk < 128; kk += 4) {
    float4 wa = *(const float4*)&sw[m][kk];
    float4 wb = *(const float4*)&sw[m + 32][kk];
    #pragma unroll
    for (int ni = 0; ni < 4; ++ni) {
      float4 pv = *(const float4*)&sp[n0 + ni][kk];
      acc[ni][0] += pv.x * wa.x + pv.y * wa.y + pv.z * wa.z + pv.w * wa.w;
      acc[ni][1] += pv.x * wb.x + pv.y * wb.y + pv.z * wb.z + pv.w * wb.w;
    }
  }
  size_t base = (size_t)blockIdx.y * 16384;
  #pragma unroll
  for (int ni = 0; ni < 4; ++ni) {
    part[base + (n0 + ni) * 512 + o0 + m] = acc[ni][0];
    part[base + (n0 + ni) * 512 + o0 + m + 32] = acc[ni][1];
  }
}

// K6: reduce 64 k-splits, apply 1/sigma1, relu -> h (32x512).
__global__ __launch_bounds__(256) void k_hred(const float* __restrict__ part, const float* __restrict__ scal,
                                              float* __restrict__ h) {
  int idx = blockIdx.x * 256 + threadIdx.x;
  float s = 0.f;
  for (int ks = 0; ks < 64; ++ks) s += part[(size_t)ks * 16384 + idx];
  float A2 = scal[2];
  float sigma = A2 / (sqrtf(A2) + 1e-12f);
  h[idx] = fmaxf(s / sigma, 0.f);
}

// K7: s = sigmoid(h.w2 / sigma2); exact top-102 via 32-bit radix select; weight = s*mask.
// One block per sample n.
__global__ __launch_bounds__(256) void k_gemm2_topk(const float* __restrict__ h, const float* __restrict__ w2,
                                                    const float* __restrict__ scal, float* __restrict__ wgt) {
  __shared__ float sh[512];
  __shared__ float ss[512];
  __shared__ unsigned sb[512];
  __shared__ int cnt;
  int n = blockIdx.x, t = threadIdx.x;
  sh[t] = h[n * 512 + t];
  sh[t + 256] = h[n * 512 + t + 256];
  __syncthreads();
  float B2 = scal[3];
  float inv_sigma = (sqrtf(B2) + 1e-12f) / B2;  // 1/sigma2
  {
    int o0 = t, o1 = t + 256;
    const float4* r0 = (const float4*)(w2 + (size_t)o0 * 512);
    const float4* r1 = (const float4*)(w2 + (size_t)o1 * 512);
    float d0 = 0.f, d1 = 0.f;
    for (int q = 0; q < 128; ++q) {
      float4 hv = *(const float4*)&sh[q * 4];
      float4 a = r0[q], b = r1[q];
      d0 += hv.x * a.x + hv.y * a.y + hv.z * a.z + hv.w * a.w;
      d1 += hv.x * b.x + hv.y * b.y + hv.z * b.z + hv.w * b.w;
    }
    float s0 = 1.f / (1.f + expf(-d0 * inv_sigma));
    float s1 = 1.f / (1.f + expf(-d1 * inv_sigma));
    ss[o0] = s0; ss[o1] = s1;
    sb[o0] = __float_as_uint(s0); sb[o1] = __float_as_uint(s1);
  }
  __syncthreads();
  // radix-select the KTOP-th largest (all s in (0,1) -> positive -> uint order == float order)
  int r = KTOP;
  unsigned prefix = 0u;
  for (int bit = 31; bit >= 0; --bit) {
    if (t == 0) cnt = 0;
    __syncthreads();
    unsigned hi = prefix | (1u << bit);
    unsigned mhi = ~((1u << bit) - 1u);
    bool m0 = (sb[t] & mhi) == hi;
    bool m1 = (sb[t + 256] & mhi) == hi;
    unsigned long long c0 = __ballot(m0);
    unsigned long long c1 = __ballot(m1);
    if ((t & 63) == 0) atomicAdd(&cnt, __popcll(c0) + __popcll(c1));
    __syncthreads();
    int c = cnt;
    __syncthreads();
    if (c >= r) prefix = hi; else r -= c;
  }
  // strictly-greater count for tie handling (jax top_k keeps lower indices first)
  if (t == 0) cnt = 0;
  __syncthreads();
  {
    unsigned long long g0 = __ballot(sb[t] > prefix);
    unsigned long long g1 = __ballot(sb[t + 256] > prefix);
    if ((t & 63) == 0) atomicAdd(&cnt, __popcll(g0) + __popcll(g1));
  }
  __syncthreads();
  int alloweq = KTOP - cnt;
  for (int e = t; e < 512; e += 256) {
    unsigned v = sb[e];
    bool keep = v > prefix;
    if (!keep && v == prefix) {
      int rank = 0;
      for (int j = 0; j < e; ++j) rank += (sb[j] == prefix);
      keep = rank < alloweq;
    }
    wgt[n * 512 + e] = keep ? ss[e] : 0.f;
  }
}

// K8: out = x * weight[n,c]. One block per plane, float4.
__global__ __launch_bounds__(256) void k_scale(const float* __restrict__ x, const float* __restrict__ wgt,
                                               float* __restrict__ out) {
  int plane = blockIdx.x;
  float g = wgt[plane];
  const float4* xi = (const float4*)(x + (size_t)plane * 3136);
  float4* oo = (float4*)(out + (size_t)plane * 3136);
  for (int e = threadIdx.x; e < 784; e += 256) {
    float4 v = xi[e];
    v.x *= g; v.y *= g; v.z *= g; v.w *= g;
    oo[e] = v;
  }
}

extern "C" void kernel_launch(void* const* d_in, const int* in_sizes, int n_in,
                              void* d_out, int out_size, void* d_ws, size_t ws_size,
                              hipStream_t stream) {
  const float* x  = (const float*)d_in[0];
  const float* w1 = (const float*)d_in[1];
  const float* w2 = (const float*)d_in[2];
  const float* u1 = (const float*)d_in[3];
  const float* u2 = (const float*)d_in[4];
  float* out = (float*)d_out;
  float* ws = (float*)d_ws;

  // ws layout (floats), all float4-aligned
  float* scal   = ws + 0;        // 4: A1, B1, A2, B2
  float* t1     = ws + 4;        // 8192
  float* t1b    = ws + 8196;     // 512
  float* p      = ws + 8708;     // 32*8192 = 262144
  float* part1  = ws + 270852;   // 8*8192 = 65536
  float* part1b = ws + 336388;   // 8*512 = 4096
  float* part   = ws + 340484;   // 64*16384 = 1048576
  float* h      = ws + 1389060;  // 16384
  float* wgt    = ws + 1405444;  // 16384
  // total 1421828 floats ~= 5.7 MB

  (void)hipMemsetAsync(scal, 0, 16, stream);
  k_pool<<<16384, 256, 0, stream>>>(x, p);
  k_sn1<<<272, 256, 0, stream>>>(w1, w2, u1, u2, part1, part1b);
  k_sn1r<<<34, 256, 0, stream>>>(part1, part1b, t1, t1b, scal);
  k_sn2<<<1024, 256, 0, stream>>>(w1, w2, t1, t1b, scal);
  k_gemm1<<<dim3(8, 64), 256, 0, stream>>>(p, w1, part);
  k_hred<<<64, 256, 0, stream>>>(part, scal, h);
  k_gemm2_topk<<<32, 256, 0, stream>>>(h, w2, scal, wgt);
  k_scale<<<16384, 256, 0, stream>>>(x, wgt, out);
}

// Round 5
// 457.571 us; speedup vs baseline: 1.1194x; 1.1194x over previous
//
#include <hip/hip_runtime.h>

// SE-block on MI355X, fused 6-dispatch pipeline.
// x: (32,512,56,56) f32, w1: (512,512,4,4), w2: (512,512,1,1), u1/u2: (512)
// A: pool+sigmoid (16384 blks) + sn1 Wt*u partials (272 blks) + scal zero
// B: gemm1 split-K partials (512 blks) + sn1r reduce->t1,||t1||^2 (34 blks)
// C: hred relu-sum (64 blks, sigma deferred) + sn2 ||Wv||^2 (1024 blks)
// D: gemm2 o-major coalesced, sigmoid((h.w2)/(s1*s2)) -> s (512 blks)
// E: top-102 exact radix select -> wgt (32 blks)
// F: out = x * wgt (16384 blks)

#define KTOP 102

__device__ __forceinline__ float block_sum256(float v) {
  __shared__ float red[4];
  #pragma unroll
  for (int off = 32; off; off >>= 1) v += __shfl_down(v, off, 64);
  int lane = threadIdx.x & 63;
  int w = threadIdx.x >> 6;
  if (lane == 0) red[w] = v;
  __syncthreads();
  float r = 0.f;
  if (threadIdx.x == 0) r = red[0] + red[1] + red[2] + red[3];
  return r;  // valid on thread 0 only
}

// A: blocks [0,16384) pool; [16384,16640) sn1-w1; [16640,16656) sn1-w2.
__global__ __launch_bounds__(256) void k_a(const float* __restrict__ x, const float* __restrict__ w1,
                                           const float* __restrict__ w2, const float* __restrict__ u1,
                                           const float* __restrict__ u2, float* __restrict__ p,
                                           float* __restrict__ part1, float* __restrict__ part1b,
                                           float* __restrict__ scal) {
  __shared__ float sx[3136];
  __shared__ float su[64];
  int b = blockIdx.x, t = threadIdx.x;
  if (b < 16384) {
    const float4* xp4 = (const float4*)(x + (size_t)b * 3136);
    float4* sx4 = (float4*)sx;
    for (int e = t; e < 784; e += 256) sx4[e] = xp4[e];
    __syncthreads();
    int w = t >> 4, lane = t & 15;
    int wr = w >> 2, wc = w & 3;
    float acc = 0.f;
    for (int e = lane; e < 196; e += 16) {
      int r = e / 14, cc = e - r * 14;
      acc += sx[(14 * wr + r) * 56 + 14 * wc + cc];
    }
    #pragma unroll
    for (int off = 8; off; off >>= 1) acc += __shfl_down(acc, off, 16);
    if (lane == 0) {
      float m = acc * (1.f / 196.f);
      p[(size_t)b * 16 + w] = 1.f / (1.f + expf(-m));
    }
  } else if (b < 16640) {
    int bb = b - 16384;
    if (bb == 0 && t < 4) scal[t] = 0.f;   // zero accumulators for B/C
    int jb = bb & 31, ic = bb >> 5;
    if (t < 64) su[t] = u1[ic * 64 + t];
    __syncthreads();
    int j = jb * 256 + t;
    const float* base = w1 + (size_t)(ic * 64) * 8192 + j;
    float acc = 0.f;
    #pragma unroll 4
    for (int i = 0; i < 64; ++i) acc += base[(size_t)i * 8192] * su[i];
    part1[ic * 8192 + j] = acc;
  } else {
    int bb = b - 16640;
    int jb = bb & 1, ic = bb >> 1;
    if (t < 64) su[t] = u2[ic * 64 + t];
    __syncthreads();
    int j = jb * 256 + t;
    const float* base = w2 + (size_t)(ic * 64) * 512 + j;
    float acc = 0.f;
    #pragma unroll 4
    for (int i = 0; i < 64; ++i) acc += base[(size_t)i * 512] * su[i];
    part1b[ic * 512 + j] = acc;
  }
}

// B: blocks [0,512) gemm1 (o-tile = b&7, k-split = b>>3); [512,544) sn1r-w1; [544,546) sn1r-w2.
__global__ __launch_bounds__(256) void k_b(const float* __restrict__ p, const float* __restrict__ w1,
                                           const float* __restrict__ part1, const float* __restrict__ part1b,
                                           float* __restrict__ part, float* __restrict__ t1,
                                           float* __restrict__ t1b, float* __restrict__ scal) {
  __shared__ float sp[32][132];
  __shared__ float sw[64][132];
  int b = blockIdx.x, t = threadIdx.x;
  if (b < 512) {
    int o0 = (b & 7) * 64;
    int k0 = (b >> 3) * 128;
    for (int idx = t; idx < 1024; idx += 256) {          // 32 rows x 32 float4
      int r = idx >> 5, c4 = (idx & 31) << 2;
      *(float4*)&sp[r][c4] = *(const float4*)&p[(size_t)r * 8192 + k0 + c4];
    }
    for (int idx = t; idx < 2048; idx += 256) {          // 64 rows x 32 float4
      int r = idx >> 5, c4 = (idx & 31) << 2;
      *(float4*)&sw[r][c4] = *(const float4*)&w1[(size_t)(o0 + r) * 8192 + k0 + c4];
    }
    __syncthreads();
    int m = t & 31, g = t >> 5;
    int n0 = g * 4;
    float acc[4][2] = {{0.f, 0.f}, {0.f, 0.f}, {0.f, 0.f}, {0.f, 0.f}};
    for (int kk = 0; kk < 128; kk += 4) {
      float4 wa = *(const float4*)&sw[m][kk];
      float4 wb = *(const float4*)&sw[m + 32][kk];
      #pragma unroll
      for (int ni = 0; ni < 4; ++ni) {
        float4 pv = *(const float4*)&sp[n0 + ni][kk];
        acc[ni][0] += pv.x * wa.x + pv.y * wa.y + pv.z * wa.z + pv.w * wa.w;
        acc[ni][1] += pv.x * wb.x + pv.y * wb.y + pv.z * wb.z + pv.w * wb.w;
      }
    }
    size_t base = (size_t)(b >> 3) * 16384;
    #pragma unroll
    for (int ni = 0; ni < 4; ++ni) {
      part[base + (n0 + ni) * 512 + o0 + m] = acc[ni][0];
      part[base + (n0 + ni) * 512 + o0 + m + 32] = acc[ni][1];
    }
  } else if (b < 544) {
    int j = (b - 512) * 256 + t;
    float s = 0.f;
    #pragma unroll
    for (int ic = 0; ic < 8; ++ic) s += part1[ic * 8192 + j];
    t1[j] = s;
    float tot = block_sum256(s * s);
    if (t == 0) atomicAdd(&scal[0], tot);
  } else {
    int j = (b - 544) * 256 + t;
    float s = 0.f;
    #pragma unroll
    for (int ic = 0; ic < 8; ++ic) s += part1b[ic * 512 + j];
    t1b[j] = s;
    float tot = block_sum256(s * s);
    if (t == 0) atomicAdd(&scal[1], tot);
  }
}

// C: blocks [0,64) hred (relu only, sigma deferred); [64,576) sn2-w1; [576,1088) sn2-w2.
__global__ __launch_bounds__(256) void k_c(const float* __restrict__ part, const float* __restrict__ w1,
                                           const float* __restrict__ w2, const float* __restrict__ t1,
                                           const float* __restrict__ t1b, float* __restrict__ h,
                                           float* __restrict__ scal) {
  int b = blockIdx.x, t = threadIdx.x;
  if (b < 64) {
    int idx = b * 256 + t;
    float s = 0.f;
    for (int ks = 0; ks < 64; ++ks) s += part[(size_t)ks * 16384 + idx];
    h[idx] = fmaxf(s, 0.f);   // h_unnorm: sigma1 applied in D (relu commutes with +scale)
  } else if (b < 576) {
    int i = b - 64;
    float inv = 1.f / (sqrtf(scal[0]) + 1e-12f);
    const float4* row = (const float4*)(w1 + (size_t)i * 8192);
    const float4* tv = (const float4*)t1;
    float acc = 0.f;
    for (int q = t; q < 2048; q += 256) {
      float4 a = row[q], v = tv[q];
      acc += a.x * v.x + a.y * v.y + a.z * v.z + a.w * v.w;
    }
    float tot = block_sum256(acc);
    if (t == 0) { float r = tot * inv; atomicAdd(&scal[2], r * r); }
  } else {
    int i = b - 576;
    float inv = 1.f / (sqrtf(scal[1]) + 1e-12f);
    const float4* row = (const float4*)(w2 + (size_t)i * 512);
    const float4* tv = (const float4*)t1b;
    float acc = 0.f;
    if (t < 128) {
      float4 a = row[t], v = tv[t];
      acc = a.x * v.x + a.y * v.y + a.z * v.z + a.w * v.w;
    }
    float tot = block_sum256(acc);
    if (t == 0) { float r = tot * inv; atomicAdd(&scal[3], r * r); }
  }
}

// D: one block per output channel o. Coalesced w2/h reads, wave shuffle-reduce.
// s[n,o] = sigmoid( (h_unnorm[n,:] . w2[o,:]) / (sigma1*sigma2) )
__global__ __launch_bounds__(256) void k_gemm2(const float* __restrict__ h, const float* __restrict__ w2,
                                               const float* __restrict__ scal, float* __restrict__ s_out) {
  int o = blockIdx.x, t = threadIdx.x;
  int w = t >> 6, lane = t & 63;
  float A2 = scal[2], B2 = scal[3];
  float sig1 = A2 / (sqrtf(A2) + 1e-12f);
  float sig2 = B2 / (sqrtf(B2) + 1e-12f);
  float inv = 1.f / (sig1 * sig2);
  const float4* wr = (const float4*)(w2 + (size_t)o * 512);
  float4 wa = wr[lane * 2], wb = wr[lane * 2 + 1];
  #pragma unroll
  for (int j = 0; j < 8; ++j) {
    int n = w * 8 + j;
    const float4* hr = (const float4*)(h + (size_t)n * 512);
    float4 ha = hr[lane * 2], hb = hr[lane * 2 + 1];
    float d = ha.x * wa.x + ha.y * wa.y + ha.z * wa.z + ha.w * wa.w
            + hb.x * wb.x + hb.y * wb.y + hb.z * wb.z + hb.w * wb.w;
    #pragma unroll
    for (int off = 32; off; off >>= 1) d += __shfl_down(d, off, 64);
    if (lane == 0) s_out[(size_t)n * 512 + o] = 1.f / (1.f + expf(-d * inv));
  }
}

// E: per-sample exact top-102 via 32-bit radix select on cached s row.
__global__ __launch_bounds__(256) void k_topk(const float* __restrict__ s_in, float* __restrict__ wgt) {
  __shared__ float ss[512];
  __shared__ unsigned sb[512];
  __shared__ int cnt;
  int n = blockIdx.x, t = threadIdx.x;
  float v0 = s_in[(size_t)n * 512 + t];
  float v1 = s_in[(size_t)n * 512 + 256 + t];
  ss[t] = v0; ss[t + 256] = v1;
  sb[t] = __float_as_uint(v0); sb[t + 256] = __float_as_uint(v1);
  __syncthreads();
  int r = KTOP;
  unsigned prefix = 0u;
  for (int bit = 31; bit >= 0; --bit) {
    if (t == 0) cnt = 0;
    __syncthreads();
    unsigned hi = prefix | (1u << bit);
    unsigned mhi = ~((1u << bit) - 1u);
    unsigned long long c0 = __ballot((sb[t] & mhi) == hi);
    unsigned long long c1 = __ballot((sb[t + 256] & mhi) == hi);
    if ((t & 63) == 0) atomicAdd(&cnt, __popcll(c0) + __popcll(c1));
    __syncthreads();
    int c = cnt;
    __syncthreads();
    if (c >= r) prefix = hi; else r -= c;
  }
  if (t == 0) cnt = 0;
  __syncthreads();
  {
    unsigned long long g0 = __ballot(sb[t] > prefix);
    unsigned long long g1 = __ballot(sb[t + 256] > prefix);
    if ((t & 63) == 0) atomicAdd(&cnt, __popcll(g0) + __popcll(g1));
  }
  __syncthreads();
  int alloweq = KTOP - cnt;   // ties: keep lowest indices first (jax top_k order)
  for (int e = t; e < 512; e += 256) {
    unsigned v = sb[e];
    bool keep = v > prefix;
    if (!keep && v == prefix) {
      int rank = 0;
      for (int j = 0; j < e; ++j) rank += (sb[j] == prefix);
      keep = rank < alloweq;
    }
    wgt[(size_t)n * 512 + e] = keep ? ss[e] : 0.f;
  }
}

// F: out = x * wgt[n,c], one block per plane.
__global__ __launch_bounds__(256) void k_scale(const float* __restrict__ x, const float* __restrict__ wgt,
                                               float* __restrict__ out) {
  int plane = blockIdx.x;
  float g = wgt[plane];
  const float4* xi = (const float4*)(x + (size_t)plane * 3136);
  float4* oo = (float4*)(out + (size_t)plane * 3136);
  for (int e = threadIdx.x; e < 784; e += 256) {
    float4 v = xi[e];
    v.x *= g; v.y *= g; v.z *= g; v.w *= g;
    oo[e] = v;
  }
}

extern "C" void kernel_launch(void* const* d_in, const int* in_sizes, int n_in,
                              void* d_out, int out_size, void* d_ws, size_t ws_size,
                              hipStream_t stream) {
  const float* x  = (const float*)d_in[0];
  const float* w1 = (const float*)d_in[1];
  const float* w2 = (const float*)d_in[2];
  const float* u1 = (const float*)d_in[3];
  const float* u2 = (const float*)d_in[4];
  float* out = (float*)d_out;
  float* ws = (float*)d_ws;

  // ws layout (floats), all float4-aligned
  float* scal   = ws + 0;        // 4: ||t1||^2, ||t1b||^2, ||t2||^2, ||t2b||^2
  float* t1     = ws + 4;        // 8192
  float* t1b    = ws + 8196;     // 512
  float* p      = ws + 8708;     // 32*8192
  float* part1  = ws + 270852;   // 8*8192
  float* part1b = ws + 336388;   // 8*512
  float* part   = ws + 340484;   // 64*16384
  float* h      = ws + 1389060;  // 16384
  float* s      = ws + 1405444;  // 16384
  float* wgt    = ws + 1421828;  // 16384

  k_a<<<16656, 256, 0, stream>>>(x, w1, w2, u1, u2, p, part1, part1b, scal);
  k_b<<<546, 256, 0, stream>>>(p, w1, part1, part1b, part, t1, t1b, scal);
  k_c<<<1088, 256, 0, stream>>>(part, w1, w2, t1, t1b, h, scal);
  k_gemm2<<<512, 256, 0, stream>>>(h, w2, scal, s);
  k_topk<<<32, 256, 0, stream>>>(s, wgt);
  k_scale<<<16384, 256, 0, stream>>>(x, wgt, out);
}